// Round 1
// baseline (327.661 us; speedup 1.0000x reference)
//
#include <hip/hip_runtime.h>
#include <hip/hip_bf16.h>

typedef __attribute__((ext_vector_type(4))) float f32x4;
typedef __attribute__((ext_vector_type(8))) short short8;

static constexpr int Ssz = 2048;
static constexpr int Dsz = 1024;

__device__ __forceinline__ unsigned short f2bf(float f){
  union { float f; unsigned u; } c; c.f = f;
  unsigned r = c.u + 0x7fffu + ((c.u >> 16) & 1u);
  return (unsigned short)(r >> 16);
}

__device__ __forceinline__ void gl2lds16(const void* g, void* l){
  __builtin_amdgcn_global_load_lds(
    (const __attribute__((address_space(1))) unsigned int*)g,
    (__attribute__((address_space(3))) unsigned int*)l, 16, 0, 0);
}

// ---------------- fp32 -> bf16 elementwise (8/thread) ----------------
__global__ void cvt_kernel(const float* __restrict__ in, unsigned short* __restrict__ out, int n){
  int i = (blockIdx.x * 256 + threadIdx.x) * 8;
  if (i >= n) return;
  float4 a = *(const float4*)(in + i);
  float4 b = *(const float4*)(in + i + 4);
  short8 o;
  o[0]=(short)f2bf(a.x); o[1]=(short)f2bf(a.y); o[2]=(short)f2bf(a.z); o[3]=(short)f2bf(a.w);
  o[4]=(short)f2bf(b.x); o[5]=(short)f2bf(b.y); o[6]=(short)f2bf(b.z); o[7]=(short)f2bf(b.w);
  *(short8*)(out + i) = o;
}

// ---------------- fp32 [R][C] -> bf16 [C][R] transpose ----------------
__global__ void transpose_kernel(const float* __restrict__ in, unsigned short* __restrict__ out,
                                 int R, int C){
  __shared__ float tile[32][33];
  int c0 = blockIdx.x * 32, r0 = blockIdx.y * 32;
  int tx = threadIdx.x, ty = threadIdx.y;
  #pragma unroll
  for (int k = 0; k < 4; ++k)
    tile[ty + 8*k][tx] = in[(size_t)(r0 + ty + 8*k) * C + c0 + tx];
  __syncthreads();
  #pragma unroll
  for (int k = 0; k < 4; ++k)
    out[(size_t)(c0 + ty + 8*k) * R + r0 + tx] = f2bf(tile[tx][ty + 8*k]);
}

// ---------------- bf16 GEMM: C[M][N] = A[M][K] * Bt[N][K]^T + bias ----------------
// mode 0: scatter to Q [B,H,S,HD] (scaled 1/8), K [B,H,S,HD], Vt [B,H,HD,S]
// mode 1: fp32 out [M][N]
#define BM 128
#define BN 128
#define BKg 64

__global__ __launch_bounds__(256, 2)
void gemm_bt(const unsigned short* __restrict__ A, const unsigned short* __restrict__ Bt,
             int M, int N, int K,
             const float* __restrict__ bias, int mode,
             unsigned short* __restrict__ Qp, unsigned short* __restrict__ Kp,
             unsigned short* __restrict__ Vtp, float* __restrict__ Out)
{
  __shared__ unsigned short ldsA[BM * BKg];
  __shared__ unsigned short ldsB[BN * BKg];
  const int tid = threadIdx.x;
  const int wid = tid >> 6;
  const int lane = tid & 63;
  const int lr = lane & 15, lg = lane >> 4;
  const int wr = wid >> 1, wc = wid & 1;
  const int m0 = blockIdx.y * BM, n0 = blockIdx.x * BN;

  const f32x4 vzero = {0.f, 0.f, 0.f, 0.f};
  f32x4 acc[4][4];
  #pragma unroll
  for (int i = 0; i < 4; ++i)
    #pragma unroll
    for (int j = 0; j < 4; ++j) acc[i][j] = vzero;

  for (int k0 = 0; k0 < K; k0 += BKg){
    __syncthreads();
    #pragma unroll
    for (int it = 0; it < 4; ++it){
      int c = it * 256 + tid;
      int row = c >> 3;
      int sc = (c & 7) ^ (row & 7);           // pre-swizzled source chunk
      gl2lds16(A  + (size_t)(m0 + row) * K + k0 + sc * 8,
               (char*)ldsA + (it * 256 + wid * 64) * 16);
      gl2lds16(Bt + (size_t)(n0 + row) * K + k0 + sc * 8,
               (char*)ldsB + (it * 256 + wid * 64) * 16);
    }
    __syncthreads();
    #pragma unroll
    for (int kc = 0; kc < 2; ++kc){
      short8 af[4], bfr[4];
      #pragma unroll
      for (int i = 0; i < 4; ++i){
        int row = wr * 64 + i * 16 + lr;
        int off = row * 128 + lg * 16 + kc * 64;
        off ^= (row & 7) << 4;
        af[i] = *(const short8*)((const char*)ldsA + off);
      }
      #pragma unroll
      for (int j = 0; j < 4; ++j){
        int row = wc * 64 + j * 16 + lr;
        int off = row * 128 + lg * 16 + kc * 64;
        off ^= (row & 7) << 4;
        bfr[j] = *(const short8*)((const char*)ldsB + off);
      }
      #pragma unroll
      for (int i = 0; i < 4; ++i)
        #pragma unroll
        for (int j = 0; j < 4; ++j)
          acc[i][j] = __builtin_amdgcn_mfma_f32_16x16x32_bf16(af[i], bfr[j], acc[i][j], 0, 0, 0);
    }
  }

  if (mode == 0){
    #pragma unroll
    for (int i = 0; i < 4; ++i)
      #pragma unroll
      for (int j = 0; j < 4; ++j)
        #pragma unroll
        for (int r = 0; r < 4; ++r){
          int gm = m0 + wr * 64 + i * 16 + lg * 4 + r;
          int gn = n0 + wc * 64 + j * 16 + lr;
          float v = acc[i][j][r] + bias[gn];
          int which = gn >> 10;
          int h = (gn >> 6) & 15;
          int hd = gn & 63;
          int b = gm >> 11;
          int s = gm & 2047;
          size_t bh = (size_t)(b * 16 + h);
          if (which == 0)      Qp[(bh * Ssz + s) * 64 + hd] = f2bf(v * 0.125f);
          else if (which == 1) Kp[(bh * Ssz + s) * 64 + hd] = f2bf(v);
          else                 Vtp[(bh * 64 + hd) * Ssz + s] = f2bf(v);
        }
  } else {
    #pragma unroll
    for (int i = 0; i < 4; ++i)
      #pragma unroll
      for (int j = 0; j < 4; ++j)
        #pragma unroll
        for (int r = 0; r < 4; ++r){
          int gm = m0 + wr * 64 + i * 16 + lg * 4 + r;
          int gn = n0 + wc * 64 + j * 16 + lr;
          Out[(size_t)gm * N + gn] = acc[i][j][r] + bias[gn];
        }
  }
}

// ---------------- causal flash attention ----------------
// grid (S/64, B*H); block 256 = 4 waves; wave w owns q rows [16w,16w+16) of the tile
__global__ __launch_bounds__(256, 2)
void attn_kernel(const unsigned short* __restrict__ Qp, const unsigned short* __restrict__ Kp,
                 const unsigned short* __restrict__ Vtp, unsigned short* __restrict__ Att)
{
  __shared__ unsigned short ldsK[64 * 64];
  __shared__ unsigned short ldsV[64 * 64];
  __shared__ unsigned short ldsP[4 * 16 * 64];
  const int tid = threadIdx.x;
  const int wid = tid >> 6;
  const int lane = tid & 63;
  const int lr = lane & 15, lg = lane >> 4;
  const int qt = blockIdx.x, bh = blockIdx.y;
  const int q0 = qt * 64;

  // Q fragments straight from global (A-layout: row=lr, k=lg*8+j)
  const unsigned short* Qbase = Qp + ((size_t)bh * Ssz + q0 + wid * 16) * 64;
  short8 aq[2];
  #pragma unroll
  for (int kc = 0; kc < 2; ++kc)
    aq[kc] = *(const short8*)(Qbase + (size_t)lr * 64 + lg * 8 + kc * 32);

  const f32x4 vzero = {0.f, 0.f, 0.f, 0.f};
  f32x4 o[4] = {vzero, vzero, vzero, vzero};
  float mrow[4] = {-1e30f, -1e30f, -1e30f, -1e30f};
  float lrow[4] = {0.f, 0.f, 0.f, 0.f};

  unsigned short* Pw = ldsP + wid * 1024;

  for (int kt = 0; kt <= qt; ++kt){
    __syncthreads();
    #pragma unroll
    for (int it = 0; it < 2; ++it){
      int c = it * 256 + tid;
      int row = c >> 3;
      int sc = (c & 7) ^ (row & 7);
      gl2lds16(Kp  + ((size_t)bh * Ssz + kt * 64 + row) * 64 + sc * 8,
               (char*)ldsK + (it * 256 + wid * 64) * 16);
      gl2lds16(Vtp + ((size_t)bh * 64 + row) * Ssz + kt * 64 + sc * 8,
               (char*)ldsV + (it * 256 + wid * 64) * 16);
    }
    __syncthreads();

    // S = Q K^T  (C-frag: row q = lg*4+r, col key = lr + 16*kf)
    f32x4 s4[4];
    #pragma unroll
    for (int kf = 0; kf < 4; ++kf){
      f32x4 s = vzero;
      #pragma unroll
      for (int kc = 0; kc < 2; ++kc){
        int row = kf * 16 + lr;
        int off = row * 128 + lg * 16 + kc * 64;
        off ^= (row & 7) << 4;
        short8 bk = *(const short8*)((const char*)ldsK + off);
        s = __builtin_amdgcn_mfma_f32_16x16x32_bf16(aq[kc], bk, s, 0, 0, 0);
      }
      s4[kf] = s;
    }

    if (kt == qt){
      #pragma unroll
      for (int kf = 0; kf < 4; ++kf)
        #pragma unroll
        for (int r = 0; r < 4; ++r)
          if (kf * 16 + lr > wid * 16 + lg * 4 + r) s4[kf][r] = -1e30f;
    }

    float pf[4][4];
    #pragma unroll
    for (int r = 0; r < 4; ++r){
      float rm = fmaxf(fmaxf(s4[0][r], s4[1][r]), fmaxf(s4[2][r], s4[3][r]));
      #pragma unroll
      for (int off = 1; off < 16; off <<= 1) rm = fmaxf(rm, __shfl_xor(rm, off, 64));
      float mn = fmaxf(mrow[r], rm);
      float scl = __expf(mrow[r] - mn);
      mrow[r] = mn;
      float rs = 0.f;
      #pragma unroll
      for (int kf = 0; kf < 4; ++kf){
        float p = __expf(s4[kf][r] - mn);
        pf[kf][r] = p;
        rs += p;
      }
      #pragma unroll
      for (int off = 1; off < 16; off <<= 1) rs += __shfl_xor(rs, off, 64);
      lrow[r] = lrow[r] * scl + rs;
      #pragma unroll
      for (int df = 0; df < 4; ++df) o[df][r] *= scl;
    }

    // P -> per-wave LDS region (swizzled), then re-read as A-fragments
    #pragma unroll
    for (int kf = 0; kf < 4; ++kf)
      #pragma unroll
      for (int r = 0; r < 4; ++r){
        int q = lg * 4 + r;
        int off = q * 128 + (kf * 16 + lr) * 2;
        off ^= (q & 7) << 4;
        *(unsigned short*)((char*)Pw + off) = f2bf(pf[kf][r]);
      }
    __syncthreads();

    #pragma unroll
    for (int kc = 0; kc < 2; ++kc){
      int offp = lr * 128 + lg * 16 + kc * 64;
      offp ^= (lr & 7) << 4;
      short8 pa = *(const short8*)((const char*)Pw + offp);
      #pragma unroll
      for (int df = 0; df < 4; ++df){
        int row = df * 16 + lr;
        int offv = row * 128 + lg * 16 + kc * 64;
        offv ^= (row & 7) << 4;
        short8 vb = *(const short8*)((const char*)ldsV + offv);
        o[df] = __builtin_amdgcn_mfma_f32_16x16x32_bf16(pa, vb, o[df], 0, 0, 0);
      }
    }
  }

  int b = bh >> 4, h = bh & 15;
  #pragma unroll
  for (int df = 0; df < 4; ++df)
    #pragma unroll
    for (int r = 0; r < 4; ++r){
      int q = q0 + wid * 16 + lg * 4 + r;
      float v = o[df][r] / lrow[r];
      Att[((size_t)(b * Ssz + q)) * Dsz + h * 64 + df * 16 + lr] = f2bf(v);
    }
}

extern "C" void kernel_launch(void* const* d_in, const int* in_sizes, int n_in,
                              void* d_out, int out_size, void* d_ws, size_t ws_size,
                              hipStream_t stream) {
  const float* x    = (const float*)d_in[0];
  const float* Wqkv = (const float*)d_in[1];
  const float* bqkv = (const float*)d_in[2];
  const float* Wout = (const float*)d_in[3];
  const float* bout = (const float*)d_in[4];
  float* out = (float*)d_out;

  unsigned short* xb    = (unsigned short*)d_ws;                 // 8192*1024
  unsigned short* wqkvT = xb    + (size_t)8192 * 1024;           // 3072*1024
  unsigned short* woutT = wqkvT + (size_t)3072 * 1024;           // 1024*1024
  unsigned short* Qb    = woutT + (size_t)1024 * 1024;           // 4*16*2048*64
  unsigned short* Kb    = Qb    + (size_t)8388608;
  unsigned short* Vtb   = Kb    + (size_t)8388608;
  unsigned short* Attb  = Vtb   + (size_t)8388608;

  cvt_kernel<<<4096, 256, 0, stream>>>(x, xb, 8388608);
  transpose_kernel<<<dim3(96, 32), dim3(32, 8), 0, stream>>>(Wqkv, wqkvT, 1024, 3072);
  transpose_kernel<<<dim3(32, 32), dim3(32, 8), 0, stream>>>(Wout, woutT, 1024, 1024);
  gemm_bt<<<dim3(24, 64), 256, 0, stream>>>(xb, wqkvT, 8192, 3072, 1024,
                                            bqkv, 0, Qb, Kb, Vtb, nullptr);
  attn_kernel<<<dim3(32, 64), 256, 0, stream>>>(Qb, Kb, Vtb, Attb);
  gemm_bt<<<dim3(8, 64), 256, 0, stream>>>(Attb, woutT, 8192, 1024, 1024,
                                           bout, 1, nullptr, nullptr, nullptr, out);
}

// Round 2
// 221.819 us; speedup vs baseline: 1.4772x; 1.4772x over previous
//
#include <hip/hip_runtime.h>
#include <hip/hip_bf16.h>

typedef __attribute__((ext_vector_type(4))) float f32x4;
typedef __attribute__((ext_vector_type(16))) float f32x16;
typedef __attribute__((ext_vector_type(8))) short short8;

static constexpr int Ssz = 2048;
static constexpr int Dsz = 1024;

__device__ __forceinline__ unsigned short f2bf(float f){
  union { float f; unsigned u; } c; c.f = f;
  unsigned r = c.u + 0x7fffu + ((c.u >> 16) & 1u);
  return (unsigned short)(r >> 16);
}

__device__ __forceinline__ void gl2lds16(const void* g, void* l){
  __builtin_amdgcn_global_load_lds(
    (const __attribute__((address_space(1))) unsigned int*)g,
    (__attribute__((address_space(3))) unsigned int*)l, 16, 0, 0);
}

__device__ __forceinline__ unsigned cvtpk(float lo, float hi){
  unsigned r;
  asm("v_cvt_pk_bf16_f32 %0, %1, %2" : "=v"(r) : "v"(lo), "v"(hi));
  return r;
}

__device__ __forceinline__ void permswap(unsigned &a, unsigned &b){
  asm volatile("v_permlane32_swap_b32 %0, %1" : "+v"(a), "+v"(b));
}

// combine x across the lane<32 / lane>=32 halves (per-query: partner holds the
// other 32 keys). After swap: a={x.lo,x.lo}, b={x.hi,x.hi}.
__device__ __forceinline__ float xmax64(float x){
  float a = x, b;
  asm volatile("v_mov_b32 %0, %1" : "=v"(b) : "v"(a));
  asm volatile("v_permlane32_swap_b32 %0, %1" : "+v"(a), "+v"(b));
  return fmaxf(a, b);
}
__device__ __forceinline__ float xsum64(float x){
  float a = x, b;
  asm volatile("v_mov_b32 %0, %1" : "=v"(b) : "v"(a));
  asm volatile("v_permlane32_swap_b32 %0, %1" : "+v"(a), "+v"(b));
  return a + b;
}

// ---------------- fp32 -> bf16 elementwise (8/thread) ----------------
__global__ void cvt_kernel(const float* __restrict__ in, unsigned short* __restrict__ out, int n){
  int i = (blockIdx.x * 256 + threadIdx.x) * 8;
  if (i >= n) return;
  float4 a = *(const float4*)(in + i);
  float4 b = *(const float4*)(in + i + 4);
  short8 o;
  o[0]=(short)f2bf(a.x); o[1]=(short)f2bf(a.y); o[2]=(short)f2bf(a.z); o[3]=(short)f2bf(a.w);
  o[4]=(short)f2bf(b.x); o[5]=(short)f2bf(b.y); o[6]=(short)f2bf(b.z); o[7]=(short)f2bf(b.w);
  *(short8*)(out + i) = o;
}

// ---------------- fp32 [R][C] -> bf16 [C][R] transpose ----------------
__global__ void transpose_kernel(const float* __restrict__ in, unsigned short* __restrict__ out,
                                 int R, int C){
  __shared__ float tile[32][33];
  int c0 = blockIdx.x * 32, r0 = blockIdx.y * 32;
  int tx = threadIdx.x, ty = threadIdx.y;
  #pragma unroll
  for (int k = 0; k < 4; ++k)
    tile[ty + 8*k][tx] = in[(size_t)(r0 + ty + 8*k) * C + c0 + tx];
  __syncthreads();
  #pragma unroll
  for (int k = 0; k < 4; ++k)
    out[(size_t)(c0 + ty + 8*k) * R + r0 + tx] = f2bf(tile[tx][ty + 8*k]);
}

// ---------------- bf16 GEMM: C[M][N] = A[M][K] * Bt[N][K]^T + bias ----------------
#define BM 128
#define BN 128
#define BKg 64

__global__ __launch_bounds__(256, 2)
void gemm_bt(const unsigned short* __restrict__ A, const unsigned short* __restrict__ Bt,
             int M, int N, int K,
             const float* __restrict__ bias, int mode,
             unsigned short* __restrict__ Qp, unsigned short* __restrict__ Kp,
             unsigned short* __restrict__ Vtp, float* __restrict__ Out)
{
  __shared__ unsigned short ldsA[BM * BKg];
  __shared__ unsigned short ldsB[BN * BKg];
  const int tid = threadIdx.x;
  const int wid = tid >> 6;
  const int lane = tid & 63;
  const int lr = lane & 15, lg = lane >> 4;
  const int wr = wid >> 1, wc = wid & 1;
  const int m0 = blockIdx.y * BM, n0 = blockIdx.x * BN;

  const f32x4 vzero = {0.f, 0.f, 0.f, 0.f};
  f32x4 acc[4][4];
  #pragma unroll
  for (int i = 0; i < 4; ++i)
    #pragma unroll
    for (int j = 0; j < 4; ++j) acc[i][j] = vzero;

  for (int k0 = 0; k0 < K; k0 += BKg){
    __syncthreads();
    #pragma unroll
    for (int it = 0; it < 4; ++it){
      int c = it * 256 + tid;
      int row = c >> 3;
      int sc = (c & 7) ^ (row & 7);
      gl2lds16(A  + (size_t)(m0 + row) * K + k0 + sc * 8,
               (char*)ldsA + (it * 256 + wid * 64) * 16);
      gl2lds16(Bt + (size_t)(n0 + row) * K + k0 + sc * 8,
               (char*)ldsB + (it * 256 + wid * 64) * 16);
    }
    __syncthreads();
    #pragma unroll
    for (int kc = 0; kc < 2; ++kc){
      short8 af[4], bfr[4];
      #pragma unroll
      for (int i = 0; i < 4; ++i){
        int row = wr * 64 + i * 16 + lr;
        int off = row * 128 + lg * 16 + kc * 64;
        off ^= (row & 7) << 4;
        af[i] = *(const short8*)((const char*)ldsA + off);
      }
      #pragma unroll
      for (int j = 0; j < 4; ++j){
        int row = wc * 64 + j * 16 + lr;
        int off = row * 128 + lg * 16 + kc * 64;
        off ^= (row & 7) << 4;
        bfr[j] = *(const short8*)((const char*)ldsB + off);
      }
      #pragma unroll
      for (int i = 0; i < 4; ++i)
        #pragma unroll
        for (int j = 0; j < 4; ++j)
          acc[i][j] = __builtin_amdgcn_mfma_f32_16x16x32_bf16(af[i], bfr[j], acc[i][j], 0, 0, 0);
    }
  }

  if (mode == 0){
    #pragma unroll
    for (int i = 0; i < 4; ++i)
      #pragma unroll
      for (int j = 0; j < 4; ++j)
        #pragma unroll
        for (int r = 0; r < 4; ++r){
          int gm = m0 + wr * 64 + i * 16 + lg * 4 + r;
          int gn = n0 + wc * 64 + j * 16 + lr;
          float v = acc[i][j][r] + bias[gn];
          int which = gn >> 10;
          int h = (gn >> 6) & 15;
          int hd = gn & 63;
          int b = gm >> 11;
          int s = gm & 2047;
          size_t bh = (size_t)(b * 16 + h);
          if (which == 0)      Qp[(bh * Ssz + s) * 64 + hd] = f2bf(v * 0.125f);
          else if (which == 1) Kp[(bh * Ssz + s) * 64 + hd] = f2bf(v);
          else                 Vtp[(bh * 64 + hd) * Ssz + s] = f2bf(v);
        }
  } else {
    #pragma unroll
    for (int i = 0; i < 4; ++i)
      #pragma unroll
      for (int j = 0; j < 4; ++j)
        #pragma unroll
        for (int r = 0; r < 4; ++r){
          int gm = m0 + wr * 64 + i * 16 + lg * 4 + r;
          int gn = n0 + wc * 64 + j * 16 + lr;
          Out[(size_t)gm * N + gn] = acc[i][j][r] + bias[gn];
        }
  }
}

// ---------------- causal flash attention, swapped-QK 32x32 ----------------
// grid (S/128, B*H); 4 waves x 32 q-rows. Sᵀ = K·Qᵀ so each lane owns one
// query column; softmax is in-register + permlane32_swap. Pᵀ packed via
// cvt_pk_bf16 + permlane32_swap feeds PV (Oᵀ = Vᵀ·Pᵀ) directly.
__global__ __launch_bounds__(256, 2)
void attn_kernel(const unsigned short* __restrict__ Qp, const unsigned short* __restrict__ Kp,
                 const unsigned short* __restrict__ Vtp, unsigned short* __restrict__ Att)
{
  __shared__ unsigned short ldsK[2][4096];
  __shared__ unsigned short ldsV[2][4096];
  const int tid = threadIdx.x;
  const int wid = tid >> 6;
  const int lane = tid & 63;
  const int lq = lane & 31;      // this lane's query column
  const int hi = lane >> 5;
  const int qt = blockIdx.x, bh = blockIdx.y;
  const int q0w = qt * 128 + wid * 32;
  const int qa = q0w + lq;
  const int nt = 2 * qt + 2;

  // Q B-fragments: lane holds Q[q0w+lq][ks*16 + 8*hi + j]
  short8 qf[4];
  {
    const unsigned short* Qb = Qp + ((size_t)bh * Ssz + q0w + lq) * 64 + hi * 8;
    #pragma unroll
    for (int ks = 0; ks < 4; ++ks) qf[ks] = *(const short8*)(Qb + ks * 16);
  }

  f32x16 Ot[2];
  #pragma unroll
  for (int d = 0; d < 2; ++d)
    #pragma unroll
    for (int r = 0; r < 16; ++r) Ot[d][r] = 0.f;
  float mrun = -3e38f, lsum = 0.f;

  // prologue: stage tile 0 into buf 0
  #pragma unroll
  for (int it = 0; it < 2; ++it){
    int c = it * 256 + tid;
    int row = c >> 3, sc = (c & 7) ^ (row & 7);
    gl2lds16(Kp  + ((size_t)bh * Ssz + row) * 64 + sc * 8,
             (char*)&ldsK[0][0] + (it * 256 + wid * 64) * 16);
    gl2lds16(Vtp + ((size_t)bh * 64 + row) * Ssz + sc * 8,
             (char*)&ldsV[0][0] + (it * 256 + wid * 64) * 16);
  }
  __syncthreads();

  for (int kt = 0; kt < nt; ++kt){
    const int cur = kt & 1;
    if (kt + 1 < nt){
      const int nxt = cur ^ 1;
      #pragma unroll
      for (int it = 0; it < 2; ++it){
        int c = it * 256 + tid;
        int row = c >> 3, sc = (c & 7) ^ (row & 7);
        gl2lds16(Kp  + ((size_t)bh * Ssz + (kt + 1) * 64 + row) * 64 + sc * 8,
                 (char*)&ldsK[nxt][0] + (it * 256 + wid * 64) * 16);
        gl2lds16(Vtp + ((size_t)bh * 64 + row) * Ssz + (kt + 1) * 64 + sc * 8,
                 (char*)&ldsV[nxt][0] + (it * 256 + wid * 64) * 16);
      }
    }

    if (kt * 64 <= q0w + 31){   // wave not fully masked for this tile
      const char* Kb = (const char*)&ldsK[cur][0];
      const char* Vb = (const char*)&ldsV[cur][0];

      // S^T = K · Q^T : S[kb] covers keys kb*32..+31 (row = key, col = q)
      f32x16 S[2];
      #pragma unroll
      for (int kb = 0; kb < 2; ++kb)
        #pragma unroll
        for (int r = 0; r < 16; ++r) S[kb][r] = 0.f;
      #pragma unroll
      for (int ks = 0; ks < 4; ++ks){
        int col = 32 * ks + 16 * hi;
        int r0 = lq, r1 = 32 + lq;
        short8 k0 = *(const short8*)(Kb + ((r0 * 128 + col) ^ ((r0 & 7) << 4)));
        short8 k1 = *(const short8*)(Kb + ((r1 * 128 + col) ^ ((r1 & 7) << 4)));
        S[0] = __builtin_amdgcn_mfma_f32_32x32x16_bf16(k0, qf[ks], S[0], 0, 0, 0);
        S[1] = __builtin_amdgcn_mfma_f32_32x32x16_bf16(k1, qf[ks], S[1], 0, 0, 0);
      }

      // causal mask: key = kt*64 + kb*32 + (r&3) + 8*(r>>2) + 4*hi
      if (kt * 64 + 63 > q0w){
        #pragma unroll
        for (int r = 0; r < 16; ++r){
          int keyb = kt * 64 + (r & 3) + ((r >> 2) << 3) + 4 * hi;
          if (keyb > qa)      S[0][r] = -3e38f;
          if (keyb + 32 > qa) S[1][r] = -3e38f;
        }
      }

      // row max: in-register tree over 32 + cross-half combine
      float t16[16];
      #pragma unroll
      for (int r = 0; r < 16; ++r) t16[r] = fmaxf(S[0][r], S[1][r]);
      float t8[8];
      #pragma unroll
      for (int r = 0; r < 8; ++r) t8[r] = fmaxf(t16[r], t16[r + 8]);
      float t4[4];
      #pragma unroll
      for (int r = 0; r < 4; ++r) t4[r] = fmaxf(t8[r], t8[r + 4]);
      float pmax = fmaxf(fmaxf(t4[0], t4[1]), fmaxf(t4[2], t4[3]));
      pmax = xmax64(pmax);

      float mn = fmaxf(mrun, pmax);
      float scl = __expf(mrun - mn);
      mrun = mn;

      #pragma unroll
      for (int kb = 0; kb < 2; ++kb)
        #pragma unroll
        for (int r = 0; r < 16; ++r) S[kb][r] = __expf(S[kb][r] - mn);

      #pragma unroll
      for (int r = 0; r < 16; ++r) t16[r] = S[0][r] + S[1][r];
      #pragma unroll
      for (int r = 0; r < 8; ++r) t8[r] = t16[r] + t16[r + 8];
      #pragma unroll
      for (int r = 0; r < 4; ++r) t4[r] = t8[r] + t8[r + 4];
      float psum = (t4[0] + t4[1]) + (t4[2] + t4[3]);
      psum = xsum64(psum);
      lsum = lsum * scl + psum;

      #pragma unroll
      for (int d = 0; d < 2; ++d)
        #pragma unroll
        for (int r = 0; r < 16; ++r) Ot[d][r] *= scl;

      // PV: O^T[d][q] += V^T[d][key] * P^T[key][q], kstep s covers keys 16s..+15
      #pragma unroll
      for (int s = 0; s < 4; ++s){
        const int b = s >> 1, s1 = s & 1;
        unsigned u0 = cvtpk(S[b][8 * s1 + 0], S[b][8 * s1 + 1]);
        unsigned u1 = cvtpk(S[b][8 * s1 + 2], S[b][8 * s1 + 3]);
        unsigned u2 = cvtpk(S[b][8 * s1 + 4], S[b][8 * s1 + 5]);
        unsigned u3 = cvtpk(S[b][8 * s1 + 6], S[b][8 * s1 + 7]);
        permswap(u0, u2);
        permswap(u1, u3);
        union { unsigned u[4]; short8 s8; } pb;
        pb.u[0] = u0; pb.u[1] = u1; pb.u[2] = u2; pb.u[3] = u3;

        int col = 32 * s + 16 * hi;
        int r0 = lq, r1 = 32 + lq;
        short8 v0 = *(const short8*)(Vb + ((r0 * 128 + col) ^ ((r0 & 7) << 4)));
        short8 v1 = *(const short8*)(Vb + ((r1 * 128 + col) ^ ((r1 & 7) << 4)));
        Ot[0] = __builtin_amdgcn_mfma_f32_32x32x16_bf16(v0, pb.s8, Ot[0], 0, 0, 0);
        Ot[1] = __builtin_amdgcn_mfma_f32_32x32x16_bf16(v1, pb.s8, Ot[1], 0, 0, 0);
      }
    }
    __syncthreads();
  }

  // epilogue: O^T/lsum -> per-wave swizzled LDS transpose -> coalesced stores
  float inv = 1.0f / lsum;
  unsigned short* ep = &ldsK[0][0] + wid * 2048;   // 4KB per wave
  #pragma unroll
  for (int d = 0; d < 2; ++d)
    #pragma unroll
    for (int g = 0; g < 4; ++g)
      #pragma unroll
      for (int cp = 0; cp < 2; ++cp){
        int r = g * 4 + cp * 2;
        unsigned w = cvtpk(Ot[d][r] * inv, Ot[d][r + 1] * inv);
        int dd = d * 32 + g * 8 + 4 * hi + cp * 2;
        int byte = lq * 128 + ((dd * 2) ^ ((lq & 7) << 4));
        *(unsigned*)((char*)ep + byte) = w;
      }
  __syncthreads();
  const int b = bh >> 4, hh = bh & 15;
  #pragma unroll
  for (int i = 0; i < 4; ++i){
    int qr = i * 8 + (lane >> 3);
    int cc = lane & 7;
    int byte = qr * 128 + ((cc * 16) ^ ((qr & 7) << 4));
    short8 vv = *(const short8*)((const char*)ep + byte);
    *(short8*)(Att + ((size_t)(b * Ssz + q0w + qr)) * Dsz + hh * 64 + cc * 8) = vv;
  }
}

extern "C" void kernel_launch(void* const* d_in, const int* in_sizes, int n_in,
                              void* d_out, int out_size, void* d_ws, size_t ws_size,
                              hipStream_t stream) {
  const float* x    = (const float*)d_in[0];
  const float* Wqkv = (const float*)d_in[1];
  const float* bqkv = (const float*)d_in[2];
  const float* Wout = (const float*)d_in[3];
  const float* bout = (const float*)d_in[4];
  float* out = (float*)d_out;

  unsigned short* xb    = (unsigned short*)d_ws;                 // 8192*1024
  unsigned short* wqkvT = xb    + (size_t)8192 * 1024;           // 3072*1024
  unsigned short* woutT = wqkvT + (size_t)3072 * 1024;           // 1024*1024
  unsigned short* Qb    = woutT + (size_t)1024 * 1024;           // [B,H,S,HD]
  unsigned short* Kb    = Qb    + (size_t)8388608;
  unsigned short* Vtb   = Kb    + (size_t)8388608;
  unsigned short* Attb  = Vtb   + (size_t)8388608;

  cvt_kernel<<<4096, 256, 0, stream>>>(x, xb, 8388608);
  transpose_kernel<<<dim3(96, 32), dim3(32, 8), 0, stream>>>(Wqkv, wqkvT, 1024, 3072);
  transpose_kernel<<<dim3(32, 32), dim3(32, 8), 0, stream>>>(Wout, woutT, 1024, 1024);
  gemm_bt<<<dim3(24, 64), 256, 0, stream>>>(xb, wqkvT, 8192, 3072, 1024,
                                            bqkv, 0, Qb, Kb, Vtb, nullptr);
  attn_kernel<<<dim3(16, 64), 256, 0, stream>>>(Qb, Kb, Vtb, Attb);
  gemm_bt<<<dim3(8, 64), 256, 0, stream>>>(Attb, woutT, 8192, 1024, 1024,
                                           bout, 1, nullptr, nullptr, nullptr, out);
}

// Round 3
// 183.934 us; speedup vs baseline: 1.7814x; 1.2060x over previous
//
#include <hip/hip_runtime.h>
#include <hip/hip_bf16.h>

typedef __attribute__((ext_vector_type(4))) float f32x4;
typedef __attribute__((ext_vector_type(16))) float f32x16;
typedef __attribute__((ext_vector_type(8))) short short8;

static constexpr int Ssz = 2048;
static constexpr int Dsz = 1024;

__device__ __forceinline__ unsigned short f2bf(float f){
  union { float f; unsigned u; } c; c.f = f;
  unsigned r = c.u + 0x7fffu + ((c.u >> 16) & 1u);
  return (unsigned short)(r >> 16);
}

__device__ __forceinline__ void gl2lds16(const void* g, void* l){
  __builtin_amdgcn_global_load_lds(
    (const __attribute__((address_space(1))) unsigned int*)g,
    (__attribute__((address_space(3))) unsigned int*)l, 16, 0, 0);
}

__device__ __forceinline__ unsigned cvtpk(float lo, float hi){
  unsigned r;
  asm("v_cvt_pk_bf16_f32 %0, %1, %2" : "=v"(r) : "v"(lo), "v"(hi));
  return r;
}

__device__ __forceinline__ void permswap(unsigned &a, unsigned &b){
  asm volatile("v_permlane32_swap_b32 %0, %1" : "+v"(a), "+v"(b));
}

__device__ __forceinline__ float xmax64(float x){
  float a = x, b;
  asm volatile("v_mov_b32 %0, %1" : "=v"(b) : "v"(a));
  asm volatile("v_permlane32_swap_b32 %0, %1" : "+v"(a), "+v"(b));
  return fmaxf(a, b);
}
__device__ __forceinline__ float xsum64(float x){
  float a = x, b;
  asm volatile("v_mov_b32 %0, %1" : "=v"(b) : "v"(a));
  asm volatile("v_permlane32_swap_b32 %0, %1" : "+v"(a), "+v"(b));
  return a + b;
}

// ---------------- fp32 -> bf16 elementwise (8/thread) ----------------
__global__ void cvt_kernel(const float* __restrict__ in, unsigned short* __restrict__ out, int n){
  int i = (blockIdx.x * 256 + threadIdx.x) * 8;
  if (i >= n) return;
  float4 a = *(const float4*)(in + i);
  float4 b = *(const float4*)(in + i + 4);
  short8 o;
  o[0]=(short)f2bf(a.x); o[1]=(short)f2bf(a.y); o[2]=(short)f2bf(a.z); o[3]=(short)f2bf(a.w);
  o[4]=(short)f2bf(b.x); o[5]=(short)f2bf(b.y); o[6]=(short)f2bf(b.z); o[7]=(short)f2bf(b.w);
  *(short8*)(out + i) = o;
}

// ---------------- fp32 [R][C] -> bf16 [C][R] transpose ----------------
__global__ void transpose_kernel(const float* __restrict__ in, unsigned short* __restrict__ out,
                                 int R, int C){
  __shared__ float tile[32][33];
  int c0 = blockIdx.x * 32, r0 = blockIdx.y * 32;
  int tx = threadIdx.x, ty = threadIdx.y;
  #pragma unroll
  for (int k = 0; k < 4; ++k)
    tile[ty + 8*k][tx] = in[(size_t)(r0 + ty + 8*k) * C + c0 + tx];
  __syncthreads();
  #pragma unroll
  for (int k = 0; k < 4; ++k)
    out[(size_t)(c0 + ty + 8*k) * R + r0 + tx] = f2bf(tile[tx][ty + 8*k]);
}

// ---------------- bf16 GEMM: C[M][N] = A[M][K] * Bt[N][K]^T + bias ----------------
#define BM 128
#define BN 128
#define BKg 64

__global__ __launch_bounds__(256, 2)
void gemm_bt(const unsigned short* __restrict__ A, const unsigned short* __restrict__ Bt,
             int M, int N, int K,
             const float* __restrict__ bias, int mode,
             unsigned short* __restrict__ Qp, unsigned short* __restrict__ Kp,
             unsigned short* __restrict__ Vtp, float* __restrict__ Out)
{
  __shared__ unsigned short ldsA[BM * BKg];
  __shared__ unsigned short ldsB[BN * BKg];
  const int tid = threadIdx.x;
  const int wid = tid >> 6;
  const int lane = tid & 63;
  const int lr = lane & 15, lg = lane >> 4;
  const int wr = wid >> 1, wc = wid & 1;
  const int m0 = blockIdx.y * BM, n0 = blockIdx.x * BN;

  const f32x4 vzero = {0.f, 0.f, 0.f, 0.f};
  f32x4 acc[4][4];
  #pragma unroll
  for (int i = 0; i < 4; ++i)
    #pragma unroll
    for (int j = 0; j < 4; ++j) acc[i][j] = vzero;

  for (int k0 = 0; k0 < K; k0 += BKg){
    __syncthreads();
    #pragma unroll
    for (int it = 0; it < 4; ++it){
      int c = it * 256 + tid;
      int row = c >> 3;
      int sc = (c & 7) ^ (row & 7);
      gl2lds16(A  + (size_t)(m0 + row) * K + k0 + sc * 8,
               (char*)ldsA + (it * 256 + wid * 64) * 16);
      gl2lds16(Bt + (size_t)(n0 + row) * K + k0 + sc * 8,
               (char*)ldsB + (it * 256 + wid * 64) * 16);
    }
    __syncthreads();
    #pragma unroll
    for (int kc = 0; kc < 2; ++kc){
      short8 af[4], bfr[4];
      #pragma unroll
      for (int i = 0; i < 4; ++i){
        int row = wr * 64 + i * 16 + lr;
        int off = row * 128 + lg * 16 + kc * 64;
        off ^= (row & 7) << 4;
        af[i] = *(const short8*)((const char*)ldsA + off);
      }
      #pragma unroll
      for (int j = 0; j < 4; ++j){
        int row = wc * 64 + j * 16 + lr;
        int off = row * 128 + lg * 16 + kc * 64;
        off ^= (row & 7) << 4;
        bfr[j] = *(const short8*)((const char*)ldsB + off);
      }
      #pragma unroll
      for (int i = 0; i < 4; ++i)
        #pragma unroll
        for (int j = 0; j < 4; ++j)
          acc[i][j] = __builtin_amdgcn_mfma_f32_16x16x32_bf16(af[i], bfr[j], acc[i][j], 0, 0, 0);
    }
  }

  if (mode == 0){
    // Q pre-scaled by 1/sqrt(HD) * log2(e) so attention works in exp2 domain
    const float qscale = 0.125f * 1.4426950408889634f;
    #pragma unroll
    for (int i = 0; i < 4; ++i)
      #pragma unroll
      for (int j = 0; j < 4; ++j)
        #pragma unroll
        for (int r = 0; r < 4; ++r){
          int gm = m0 + wr * 64 + i * 16 + lg * 4 + r;
          int gn = n0 + wc * 64 + j * 16 + lr;
          float v = acc[i][j][r] + bias[gn];
          int which = gn >> 10;
          int h = (gn >> 6) & 15;
          int hd = gn & 63;
          int b = gm >> 11;
          int s = gm & 2047;
          size_t bh = (size_t)(b * 16 + h);
          if (which == 0)      Qp[(bh * Ssz + s) * 64 + hd] = f2bf(v * qscale);
          else if (which == 1) Kp[(bh * Ssz + s) * 64 + hd] = f2bf(v);
          else                 Vtp[(bh * 64 + hd) * Ssz + s] = f2bf(v);
        }
  } else {
    #pragma unroll
    for (int i = 0; i < 4; ++i)
      #pragma unroll
      for (int j = 0; j < 4; ++j)
        #pragma unroll
        for (int r = 0; r < 4; ++r){
          int gm = m0 + wr * 64 + i * 16 + lg * 4 + r;
          int gn = n0 + wc * 64 + j * 16 + lr;
          Out[(size_t)gm * N + gn] = acc[i][j][r] + bias[gn];
        }
  }
}

// ---------------- causal flash attention, swapped-QK 32x32, balanced ----------------
// grid (8, B*H); block bx handles q-tiles bx and 15-bx => exactly 34 K-tile units
// per block; 512 equal blocks = 2 resident blocks/CU, no tail.
__global__ __launch_bounds__(256, 2)
void attn_kernel(const unsigned short* __restrict__ Qp, const unsigned short* __restrict__ Kp,
                 const unsigned short* __restrict__ Vtp, unsigned short* __restrict__ Att)
{
  __shared__ unsigned short ldsK[2][4096];
  __shared__ unsigned short ldsV[2][4096];
  const int tid = threadIdx.x;
  const int wid = tid >> 6;
  const int lane = tid & 63;
  const int lq = lane & 31;      // this lane's query column
  const int hi = lane >> 5;
  const int bh = blockIdx.y;
  const int b = bh >> 4, hh = bh & 15;

  #pragma unroll 1
  for (int job = 0; job < 2; ++job){
    const int qt = job ? (15 - (int)blockIdx.x) : (int)blockIdx.x;
    const int q0w = qt * 128 + wid * 32;
    const int qa = q0w + lq;
    const int nt = 2 * qt + 2;

    // Q B-fragments: lane holds Q[q0w+lq][ks*16 + 8*hi + j] (pre-scaled, log2e folded)
    short8 qf[4];
    {
      const unsigned short* Qb = Qp + ((size_t)bh * Ssz + q0w + lq) * 64 + hi * 8;
      #pragma unroll
      for (int ks = 0; ks < 4; ++ks) qf[ks] = *(const short8*)(Qb + ks * 16);
    }

    f32x16 Ot[2];
    #pragma unroll
    for (int d = 0; d < 2; ++d)
      #pragma unroll
      for (int r = 0; r < 16; ++r) Ot[d][r] = 0.f;
    float mrun = -3e38f, lsum = 0.f;

    // prologue: stage tile 0 into buf 0
    #pragma unroll
    for (int it = 0; it < 2; ++it){
      int c = it * 256 + tid;
      int row = c >> 3, sc = (c & 7) ^ (row & 7);
      gl2lds16(Kp  + ((size_t)bh * Ssz + row) * 64 + sc * 8,
               (char*)&ldsK[0][0] + (it * 256 + wid * 64) * 16);
      gl2lds16(Vtp + ((size_t)bh * 64 + row) * Ssz + sc * 8,
               (char*)&ldsV[0][0] + (it * 256 + wid * 64) * 16);
    }
    __syncthreads();

    for (int kt = 0; kt < nt; ++kt){
      const int cur = kt & 1;
      if (kt + 1 < nt){
        const int nxt = cur ^ 1;
        #pragma unroll
        for (int it = 0; it < 2; ++it){
          int c = it * 256 + tid;
          int row = c >> 3, sc = (c & 7) ^ (row & 7);
          gl2lds16(Kp  + ((size_t)bh * Ssz + (kt + 1) * 64 + row) * 64 + sc * 8,
                   (char*)&ldsK[nxt][0] + (it * 256 + wid * 64) * 16);
          gl2lds16(Vtp + ((size_t)bh * 64 + row) * Ssz + (kt + 1) * 64 + sc * 8,
                   (char*)&ldsV[nxt][0] + (it * 256 + wid * 64) * 16);
        }
      }

      if (kt * 64 <= q0w + 31){   // wave not fully masked for this tile
        const char* Kb = (const char*)&ldsK[cur][0];
        const char* Vb = (const char*)&ldsV[cur][0];

        // S^T = K · Q^T : S[kb] covers keys kb*32..+31 (row = key, col = q)
        f32x16 S[2];
        #pragma unroll
        for (int kb = 0; kb < 2; ++kb)
          #pragma unroll
          for (int r = 0; r < 16; ++r) S[kb][r] = 0.f;
        #pragma unroll
        for (int ks = 0; ks < 4; ++ks){
          int col = 32 * ks + 16 * hi;
          int r0 = lq, r1 = 32 + lq;
          short8 k0 = *(const short8*)(Kb + ((r0 * 128 + col) ^ ((r0 & 7) << 4)));
          short8 k1 = *(const short8*)(Kb + ((r1 * 128 + col) ^ ((r1 & 7) << 4)));
          S[0] = __builtin_amdgcn_mfma_f32_32x32x16_bf16(k0, qf[ks], S[0], 0, 0, 0);
          S[1] = __builtin_amdgcn_mfma_f32_32x32x16_bf16(k1, qf[ks], S[1], 0, 0, 0);
        }

        // causal mask: key = kt*64 + kb*32 + (r&3) + 8*(r>>2) + 4*hi
        if (kt * 64 + 63 > q0w){
          #pragma unroll
          for (int r = 0; r < 16; ++r){
            int keyb = kt * 64 + (r & 3) + ((r >> 2) << 3) + 4 * hi;
            if (keyb > qa)      S[0][r] = -3e38f;
            if (keyb + 32 > qa) S[1][r] = -3e38f;
          }
        }

        // row max: in-register tree + cross-half combine
        float t16[16];
        #pragma unroll
        for (int r = 0; r < 16; ++r) t16[r] = fmaxf(S[0][r], S[1][r]);
        float t8[8];
        #pragma unroll
        for (int r = 0; r < 8; ++r) t8[r] = fmaxf(t16[r], t16[r + 8]);
        float t4[4];
        #pragma unroll
        for (int r = 0; r < 4; ++r) t4[r] = fmaxf(t8[r], t8[r + 4]);
        float pmax = fmaxf(fmaxf(t4[0], t4[1]), fmaxf(t4[2], t4[3]));
        pmax = xmax64(pmax);

        // defer-max (T13): skip O-rescale while tile max stays within 2^8
        if (!__all(pmax - mrun <= 8.0f)){
          float mn = fmaxf(mrun, pmax);
          float scl = __builtin_amdgcn_exp2f(mrun - mn);
          mrun = mn;
          lsum *= scl;
          #pragma unroll
          for (int d = 0; d < 2; ++d)
            #pragma unroll
            for (int r = 0; r < 16; ++r) Ot[d][r] *= scl;
        }

        #pragma unroll
        for (int kb = 0; kb < 2; ++kb)
          #pragma unroll
          for (int r = 0; r < 16; ++r)
            S[kb][r] = __builtin_amdgcn_exp2f(S[kb][r] - mrun);

        #pragma unroll
        for (int r = 0; r < 16; ++r) t16[r] = S[0][r] + S[1][r];
        #pragma unroll
        for (int r = 0; r < 8; ++r) t8[r] = t16[r] + t16[r + 8];
        #pragma unroll
        for (int r = 0; r < 4; ++r) t4[r] = t8[r] + t8[r + 4];
        float psum = (t4[0] + t4[1]) + (t4[2] + t4[3]);
        psum = xsum64(psum);
        lsum += psum;

        // PV: O^T[d][q] += V^T[d][key] * P^T[key][q]
        #pragma unroll
        for (int s = 0; s < 4; ++s){
          const int sb = s >> 1, s1 = s & 1;
          unsigned u0 = cvtpk(S[sb][8 * s1 + 0], S[sb][8 * s1 + 1]);
          unsigned u1 = cvtpk(S[sb][8 * s1 + 2], S[sb][8 * s1 + 3]);
          unsigned u2 = cvtpk(S[sb][8 * s1 + 4], S[sb][8 * s1 + 5]);
          unsigned u3 = cvtpk(S[sb][8 * s1 + 6], S[sb][8 * s1 + 7]);
          permswap(u0, u2);
          permswap(u1, u3);
          union { unsigned u[4]; short8 s8; } pb;
          pb.u[0] = u0; pb.u[1] = u1; pb.u[2] = u2; pb.u[3] = u3;

          int col = 32 * s + 16 * hi;
          int r0 = lq, r1 = 32 + lq;
          short8 v0 = *(const short8*)(Vb + ((r0 * 128 + col) ^ ((r0 & 7) << 4)));
          short8 v1 = *(const short8*)(Vb + ((r1 * 128 + col) ^ ((r1 & 7) << 4)));
          Ot[0] = __builtin_amdgcn_mfma_f32_32x32x16_bf16(v0, pb.s8, Ot[0], 0, 0, 0);
          Ot[1] = __builtin_amdgcn_mfma_f32_32x32x16_bf16(v1, pb.s8, Ot[1], 0, 0, 0);
        }
      }
      __syncthreads();
    }

    // epilogue: O^T/lsum -> per-wave swizzled LDS transpose -> coalesced stores
    float inv = 1.0f / lsum;
    unsigned short* ep = &ldsK[0][0] + wid * 2048;   // 4KB per wave
    #pragma unroll
    for (int d = 0; d < 2; ++d)
      #pragma unroll
      for (int g = 0; g < 4; ++g)
        #pragma unroll
        for (int cp = 0; cp < 2; ++cp){
          int r = g * 4 + cp * 2;
          unsigned w = cvtpk(Ot[d][r] * inv, Ot[d][r + 1] * inv);
          int dd = d * 32 + g * 8 + 4 * hi + cp * 2;
          int byte = lq * 128 + ((dd * 2) ^ ((lq & 7) << 4));
          *(unsigned*)((char*)ep + byte) = w;
        }
    __syncthreads();
    #pragma unroll
    for (int i = 0; i < 4; ++i){
      int qr = i * 8 + (lane >> 3);
      int cc = lane & 7;
      int byte = qr * 128 + ((cc * 16) ^ ((qr & 7) << 4));
      short8 vv = *(const short8*)((const char*)ep + byte);
      *(short8*)(Att + ((size_t)(b * Ssz + q0w + qr)) * Dsz + hh * 64 + cc * 8) = vv;
    }
    __syncthreads();   // protect epilogue scratch before next job's staging
  }
}

extern "C" void kernel_launch(void* const* d_in, const int* in_sizes, int n_in,
                              void* d_out, int out_size, void* d_ws, size_t ws_size,
                              hipStream_t stream) {
  const float* x    = (const float*)d_in[0];
  const float* Wqkv = (const float*)d_in[1];
  const float* bqkv = (const float*)d_in[2];
  const float* Wout = (const float*)d_in[3];
  const float* bout = (const float*)d_in[4];
  float* out = (float*)d_out;

  unsigned short* xb    = (unsigned short*)d_ws;                 // 8192*1024
  unsigned short* wqkvT = xb    + (size_t)8192 * 1024;           // 3072*1024
  unsigned short* woutT = wqkvT + (size_t)3072 * 1024;           // 1024*1024
  unsigned short* Qb    = woutT + (size_t)1024 * 1024;           // [B,H,S,HD]
  unsigned short* Kb    = Qb    + (size_t)8388608;
  unsigned short* Vtb   = Kb    + (size_t)8388608;
  unsigned short* Attb  = Vtb   + (size_t)8388608;

  cvt_kernel<<<4096, 256, 0, stream>>>(x, xb, 8388608);
  transpose_kernel<<<dim3(96, 32), dim3(32, 8), 0, stream>>>(Wqkv, wqkvT, 1024, 3072);
  transpose_kernel<<<dim3(32, 32), dim3(32, 8), 0, stream>>>(Wout, woutT, 1024, 1024);
  gemm_bt<<<dim3(24, 64), 256, 0, stream>>>(xb, wqkvT, 8192, 3072, 1024,
                                            bqkv, 0, Qb, Kb, Vtb, nullptr);
  attn_kernel<<<dim3(8, 64), 256, 0, stream>>>(Qb, Kb, Vtb, Attb);
  gemm_bt<<<dim3(8, 64), 256, 0, stream>>>(Attb, woutT, 8192, 1024, 1024,
                                           bout, 1, nullptr, nullptr, nullptr, out);
}